// Round 7
// baseline (230.987 us; speedup 1.0000x reference)
//
#include <hip/hip_runtime.h>

// B=16 images, A=65536 anchors, G=32 gts. Inputs float32; output slot read as
// bf16 low-16-bits (dual-encode store gives absmax 0.0 -> keep it).
#define BB 16
#define AA 65536
#define GG 32
// Histogram: key = (float_bits>>14) - KOFF, bin 0 == 2^-10, 512 bins/octave.
// Count-only, value = bin midpoint (rel err <= 2^-10 << 2% budget).
#define NB 8192
#define KOFF 59904u          // __float_as_uint(2^-10) >> 14
#define AT 4                 // anchors per thread in k_matchforce
#define APB (256 * AT)       // 1024 anchors per block
#define MBLK (AA / APB)      // 64 match blocks per image
#define NSEG 64              // stats segments per image (R6: 16 -> 64, 4 blk/CU)
#define SEGA (AA / NSEG)     // 1024 anchors per stats block

// Static scratch: fully rewritten every call before any read. Re-poison safe.
__device__ unsigned char g_mask[(size_t)BB * AA];
__device__ unsigned char g_bidx[(size_t)BB * AA];
__device__ float g_spart[BB * NSEG * 2];   // pos, loc partials
__device__ int   g_npart[BB * NSEG];
__device__ float g_loc[BB], g_pos[BB], g_neg[BB];
__device__ int   g_npos[BB], g_nneg[BB];

// Dynamic scratch, zeroed by ONE hipMemsetAsync each call:
// [0, BB*NB)            u32 per-image histograms (direct global atomicAdd)
// [BB*NB, +BB*GG*2)     u64 per-(b,g) force-match keys (global atomicMax)
// [+2]                  done counter for the last-block final combine
#define DYN_U32 (BB * NB + BB * GG * 2 + 2)
__device__ unsigned int g_dyn[DYN_U32];
__device__ __forceinline__ unsigned int* histp(int b) {
    return g_dyn + (size_t)b * NB;
}
__device__ __forceinline__ unsigned long long* fkeyp() {
    return (unsigned long long*)(g_dyn + BB * NB);   // byte off 524288, 8-aligned
}
__device__ __forceinline__ int* donep() {
    return (int*)(g_dyn + BB * NB + BB * GG * 2);
}

__device__ __forceinline__ float midval(int bin) {
    return __uint_as_float((((unsigned int)bin + KOFF) << 14) | 8192u);
}

// ---------------------------------------------------------------------------
// Kernel 1: fused per-anchor match + per-gt force-match.
// grid (MBLK, B), block 256, AT=4 anchors/thread (strided, coalesced).
// Divide-free scoring: r = inter/(areaA+areaG), monotone in IoU (iou=r/(1-r)),
// argmax-equivalent; iou>0.5 <=> r>1/3. rcp 1-ulp absorbed by bf16 budget
// (R2-R6 benches: absmax 0.0).
// Reduction (R6-proven): per gt, thread reduces its 4 candidates in registers
// to key=(r_bits<<32)|(~offset) (tie-break = lowest offset, exact), 6-level
// __shfl_xor u64 butterfly, lane0 -> wkey[wave][g]; after barrier t<32 folds
// the 4 wave partials and fires ONE global atomicMax into fkey[b][g] with the
// GLOBAL anchor id in the low word (64 blocks/image x 32 keys: negligible
// contention; replaces the g_fpart partial array + downstream folds).
__global__ void __launch_bounds__(256, 4)
k_matchforce(const float4* __restrict__ anchors,
             const float4* __restrict__ gts) {
    __shared__ float4 sg[GG];
    __shared__ unsigned long long wkey[4][GG];
    const int b = blockIdx.y;
    const int t = threadIdx.x;
    const int wave = t >> 6, lane = t & 63;
    if (t < GG) sg[t] = gts[(size_t)b * GG + t];
    __syncthreads();

    const size_t abase = (size_t)b * AA + (size_t)blockIdx.x * APB;

    float ax0[AT], ay0[AT], ax1[AT], ay1[AT], aar[AT], best[AT];
    int bg[AT];
#pragma unroll
    for (int j = 0; j < AT; ++j) {
        const float4 av = anchors[abase + j * 256 + t];
        ax0[j] = av.x; ay0[j] = av.y; ax1[j] = av.z; ay1[j] = av.w;
        aar[j] = (av.z - av.x) * (av.w - av.y);
        best[j] = -1.0f; bg[j] = 0;
    }

#pragma unroll 2
    for (int g = 0; g < GG; ++g) {
        const float4 gb = sg[g];
        const float ga = (gb.z - gb.x) * (gb.w - gb.y);
        float fbest = -1.0f;              // r >= 0 always -> j=0 wins init
        int fo = t;                       // block-local offset of j=0 anchor
#pragma unroll
        for (int j = 0; j < AT; ++j) {
            const float lx = fmaxf(ax0[j], gb.x), ly = fmaxf(ay0[j], gb.y);
            const float rx = fminf(ax1[j], gb.z), ry = fminf(ay1[j], gb.w);
            const float w = fmaxf(rx - lx, 0.0f), h = fmaxf(ry - ly, 0.0f);
            const float inter = w * h;
            const float s = aar[j] + ga;                    // areaA + areaG > 0
            const float r = inter * __builtin_amdgcn_rcpf(s);
            if (r > best[j]) { best[j] = r; bg[j] = g; }    // strict >: first max
            if (r > fbest)   { fbest = r; fo = j * 256 + t; }
        }
        // packed key: fbest >= 0 so float bits are unsigned-monotone; low word
        // = ~offset so larger key == smaller anchor offset on value ties.
        unsigned long long key =
            ((unsigned long long)__float_as_uint(fbest) << 32) |
            (unsigned long long)(0xFFFFFFFFu - (unsigned int)fo);
#pragma unroll
        for (int off = 1; off < 64; off <<= 1) {
            const unsigned long long o = __shfl_xor(key, off, 64);
            if (o > key) key = o;
        }
        if (lane == 0) wkey[wave][g] = key;
    }

#pragma unroll
    for (int j = 0; j < AT; ++j) {
        g_mask[abase + j * 256 + t] = (best[j] > (1.0f / 3.0f)) ? 1 : 0;
        g_bidx[abase + j * 256 + t] = (unsigned char)bg[j];
    }
    __syncthreads();
    if (t < GG) {
        unsigned long long k = wkey[0][t];
#pragma unroll
        for (int w = 1; w < 4; ++w) {
            const unsigned long long k1 = wkey[w][t];
            if (k1 > k) k = k1;
        }
        // re-pack low word with the GLOBAL anchor id; fire one device atomic.
        const unsigned int off = 0xFFFFFFFFu - (unsigned int)(k & 0xFFFFFFFFull);
        const unsigned int ga = (unsigned int)(blockIdx.x * APB) + off;
        atomicMax(&fkeyp()[b * GG + t],
                  (k & 0xFFFFFFFF00000000ull) |
                  (unsigned long long)(0xFFFFFFFFu - ga));
    }
}

// ---------------------------------------------------------------------------
// Kernel 2: segmented per-image stats. grid (NSEG=64, B), block 256 ->
// 1024 blocks (4/CU, 16 waves/CU; was 1 blk/CU at NSEG=16).
// Forced positives: read the 32 folded fkeys directly (256 B), mark in-segment
// winners in a 128 B LDS bitmap. Positive = g_mask OR bitmap bit.
// Negatives: bin straight into the global per-image u32 hist (fire-and-forget
// atomicAdd; hot bin ~23 hits/image -> no contention). No LDS hist, no 4 MB
// partial writeout. Integer atomics: bit-exact regardless of order.
__global__ void k_stats(const float4* __restrict__ bbox,
                        const float* __restrict__ conf,
                        const float4* __restrict__ gts) {
    __shared__ float4 sg[GG];
    __shared__ unsigned int bmap[SEGA / 32];  // 128 B forced-positive bitmap
    __shared__ float rf[256], rf2[256];
    __shared__ unsigned int ru[256];
    const int b = blockIdx.y, seg = blockIdx.x, t = threadIdx.x;
    if (t < GG) sg[t] = gts[(size_t)b * GG + t];
    if (t < SEGA / 32) bmap[t] = 0u;
    __syncthreads();
    if (t < GG) {
        const unsigned long long k = fkeyp()[b * GG + t];
        const unsigned int a = 0xFFFFFFFFu - (unsigned int)(k & 0xFFFFFFFFull);
        const int la = (int)a - seg * SEGA;
        if (la >= 0 && la < SEGA) atomicOr(&bmap[la >> 5], 1u << (la & 31));
    }
    __syncthreads();

    const size_t base = (size_t)b * AA + (size_t)seg * SEGA;   // anchor units
    const float4* c4 = (const float4*)(conf + base);
    const uchar4* m4 = (const uchar4*)(g_mask + base);
    const uchar4* x4 = (const uchar4*)(g_bidx + base);
    const float4* bb4 = bbox + base;
    unsigned int* hb = histp(b);

    float pos = 0.0f, loc = 0.0f;
    int np = 0;
    {
        const int idx = t;                     // 4 consecutive anchors/thread
        const float4 p4 = c4[idx];
        const uchar4 mm = m4[idx];
        const uchar4 xx = x4[idx];
        const unsigned int bw = (bmap[idx >> 3] >> ((idx & 7) * 4)) & 0xFu;
        const float pv[4] = {p4.x, p4.y, p4.z, p4.w};
        const unsigned char mv[4] = {mm.x, mm.y, mm.z, mm.w};
        const unsigned char xv[4] = {xx.x, xx.y, xx.z, xx.w};
#pragma unroll
        for (int c = 0; c < 4; ++c) {
            const float p = pv[c];
            if (mv[c] | ((bw >> c) & 1u)) {
                np += 1;
                pos += -logf(p);
                const float4 bv = bb4[4 * idx + c];
                const float4 gb = sg[xv[c]];
                const float d0 = (bv.x + bv.z) * 0.5f - (gb.x + gb.z) * 0.5f;
                const float d1 = (bv.y + bv.w) * 0.5f - (gb.y + gb.w) * 0.5f;
                const float d2 = (bv.z - bv.x) - (gb.z - gb.x);
                const float d3 = (bv.w - bv.y) - (gb.w - gb.y);
                float ds[4] = {d0, d1, d2, d3};
#pragma unroll
                for (int q = 0; q < 4; ++q) {
                    float ax = fabsf(ds[q]);
                    loc += (ax < 1.0f) ? 0.5f * ax * ax : ax - 0.5f;
                }
            } else {
                const float nb = -log1pf(-p);
                int key = (int)(__float_as_uint(nb) >> 14) - (int)KOFF;
                key = key < 0 ? 0 : (key > NB - 1 ? NB - 1 : key);
                atomicAdd(&hb[key], 1u);       // fire-and-forget, device scope
            }
        }
    }
    // block reduce np/pos/loc
    ru[t] = (unsigned int)np; rf[t] = pos; rf2[t] = loc;
    __syncthreads();
    for (int w = 128; w > 0; w >>= 1) {
        if (t < w) { ru[t] += ru[t + w]; rf[t] += rf[t + w]; rf2[t] += rf2[t + w]; }
        __syncthreads();
    }
    if (t == 0) {
        g_npart[b * NSEG + seg] = (int)ru[0];
        g_spart[(b * NSEG + seg) * 2 + 0] = rf[0];
        g_spart[(b * NSEG + seg) * 2 + 1] = rf2[0];
    }
}

// ---------------------------------------------------------------------------
// Kernel 3: per-image hard-negative top-k + (last block) final combine.
// grid B, block 1024. Reads the 32 KB u32 hist directly (uint4 loads) -- the
// 4 MB partial fold is gone. Seg partials folded wave-parallel (t<64 + shfl).
// Cross-block handoff unchanged: __threadfence + done counter; 16th block
// agent-scope loads and writes the dual-bf16-encoded output.
__global__ void __launch_bounds__(1024) k_select(unsigned int* __restrict__ out) {
    __shared__ unsigned int hist[NB];         // 32 KB
    __shared__ unsigned int ru[1024];
    __shared__ unsigned int s2[32];
    __shared__ float sh_pos, sh_loc;
    __shared__ int sh_np, sh_k, sh_bsel;
    __shared__ unsigned int sh_take;
    __shared__ float rf[1024];

    const int b = blockIdx.x, t = threadIdx.x;
    {
        const uint4* h4 = (const uint4*)histp(b);
#pragma unroll
        for (int w = 0; w < 2; ++w) {
            const int i = w * 1024 + t;       // NB/4 = 2048 uint4
            const uint4 v = h4[i];
            hist[4 * i + 0] = v.x; hist[4 * i + 1] = v.y;
            hist[4 * i + 2] = v.z; hist[4 * i + 3] = v.w;
        }
    }
    if (t < 64) {                             // wave-parallel seg-partial fold
        int np = g_npart[b * NSEG + t];
        float pos = g_spart[(b * NSEG + t) * 2 + 0];
        float loc = g_spart[(b * NSEG + t) * 2 + 1];
#pragma unroll
        for (int off = 32; off > 0; off >>= 1) {
            np  += __shfl_xor(np,  off, 64);
            pos += __shfl_xor(pos, off, 64);
            loc += __shfl_xor(loc, off, 64);
        }
        if (t == 0) { sh_np = np; sh_pos = pos; sh_loc = loc; }
    }
    __syncthreads();
    const int np_tot = sh_np;

    // descending chunk counts: thread t covers bins NB-1-8t .. NB-8-8t
    unsigned int c = 0;
    const int hi = NB - 1 - t * 8;
#pragma unroll
    for (int j = 0; j < 8; ++j) c += hist[hi - j];
    ru[t] = c;
    __syncthreads();
    if (t < 32) {
        unsigned int x = 0;
#pragma unroll
        for (int j = 0; j < 32; ++j) x += ru[t * 32 + j];
        s2[t] = x;
    }
    __syncthreads();
    if (t == 0) {
        int k = 3 * np_tot;
        const int maxneg = AA - np_tot;
        if (k > maxneg) k = maxneg;
        sh_k = k;
        int bsel = NB;            // NB => nothing selected
        unsigned int take = 0;
        if (k > 0) {
            unsigned int cum = 0;
            int u = 0;
            while (u < 31 && cum + s2[u] < (unsigned int)k) { cum += s2[u]; ++u; }
            int cc = u * 32;
            while (cc < 1023 && cum + ru[cc] < (unsigned int)k) { cum += ru[cc]; ++cc; }
            const int h2 = NB - 1 - cc * 8;
            int j = 0;
            while (j < 7 && cum + hist[h2 - j] < (unsigned int)k) { cum += hist[h2 - j]; ++j; }
            bsel = h2 - j;
            take = (unsigned int)k - cum;
        }
        sh_bsel = bsel; sh_take = take;
    }
    __syncthreads();
    const int bsel = sh_bsel;
    float negp = 0.0f;
    for (int j = t; j < NB; j += 1024)
        if (j > bsel) { unsigned int cnt = hist[j]; if (cnt) negp += (float)cnt * midval(j); }
    rf[t] = negp;
    __syncthreads();
    for (int w = 512; w > 0; w >>= 1) {
        if (t < w) rf[t] += rf[t + w];
        __syncthreads();
    }
    if (t == 0) {
        float neg = 0.0f;
        if (sh_k > 0) neg = rf[0] + (float)sh_take * midval(bsel < NB ? bsel : 0);
        g_loc[b] = sh_loc; g_pos[b] = sh_pos; g_neg[b] = neg;
        g_npos[b] = np_tot; g_nneg[b] = sh_k;

        __threadfence();                        // publish before counting in
        const int old = atomicAdd(donep(), 1);
        if (old == BB - 1) {                    // last image: final combine
            __threadfence();
            float loc = 0.0f, conf = 0.0f;
            int tot = 0;
            for (int bb = 0; bb < BB; ++bb) {
                const float lv = __hip_atomic_load(&g_loc[bb],  __ATOMIC_RELAXED, __HIP_MEMORY_SCOPE_AGENT);
                const float pv = __hip_atomic_load(&g_pos[bb],  __ATOMIC_RELAXED, __HIP_MEMORY_SCOPE_AGENT);
                const float nv = __hip_atomic_load(&g_neg[bb],  __ATOMIC_RELAXED, __HIP_MEMORY_SCOPE_AGENT);
                const int   np = __hip_atomic_load(&g_npos[bb], __ATOMIC_RELAXED, __HIP_MEMORY_SCOPE_AGENT);
                const int   nn = __hip_atomic_load(&g_nneg[bb], __ATOMIC_RELAXED, __HIP_MEMORY_SCOPE_AGENT);
                loc += lv;
                conf += pv / (float)(np > 1 ? np : 1) +
                        nv / (float)(nn > 1 ? nn : 1);
                tot += np;
            }
            const float total = loc / (float)(tot > 1 ? tot : 1) + conf / (float)BB;
            const unsigned int u = __float_as_uint(total);
            const unsigned int r = 0x7FFFu + ((u >> 16) & 1u);
            const unsigned int bf = (u + r) >> 16;      // bf16(total), RNE
            out[0] = (bf << 16) | bf;
        }
    }
}

extern "C" void kernel_launch(void* const* d_in, const int* in_sizes, int n_in,
                              void* d_out, int out_size, void* d_ws, size_t ws_size,
                              hipStream_t stream) {
    const float4* bbox    = (const float4*)d_in[0];
    const float*  conf    = (const float*)d_in[1];
    const float4* anchors = (const float4*)d_in[2];
    const float4* gts     = (const float4*)d_in[3];

    static unsigned int* dynp = nullptr;       // cached symbol address
    if (!dynp) hipGetSymbolAddress((void**)&dynp, HIP_SYMBOL(g_dyn));
    hipMemsetAsync(dynp, 0, sizeof(unsigned int) * DYN_U32, stream);

    k_matchforce<<<dim3(MBLK, BB), 256, 0, stream>>>(anchors, gts);
    k_stats<<<dim3(NSEG, BB), 256, 0, stream>>>(bbox, conf, gts);
    k_select<<<BB, 1024, 0, stream>>>((unsigned int*)d_out);
}

// Round 8
// 141.717 us; speedup vs baseline: 1.6299x; 1.6299x over previous
//
#include <hip/hip_runtime.h>

// B=16 images, A=65536 anchors, G=32 gts. Inputs float32; output slot read as
// bf16 low-16-bits (dual-encode store gives absmax 0.0 -> keep it).
#define BB 16
#define AA 65536
#define GG 32
// Histogram: key = (float_bits>>14) - KOFF, bin 0 == 2^-10, 512 bins/octave.
// Count-only, value = bin midpoint (rel err <= 2^-10 << 2% budget).
#define NB 8192
#define KOFF 59904u          // __float_as_uint(2^-10) >> 14
#define AT 4                 // anchors per thread in k_matchforce
#define APB (256 * AT)       // 1024 anchors per block
#define MBLK (AA / APB)      // 64 match blocks per image
#define NSEG 64              // stats segments per image (4 blk/CU occupancy)
#define SEGA (AA / NSEG)     // 1024 anchors per stats block

// Static scratch: fully rewritten every call before any read. Re-poison safe.
__device__ unsigned char g_mask[(size_t)BB * AA];
__device__ unsigned char g_bidx[(size_t)BB * AA];
__device__ unsigned int  g_hpart[(size_t)BB * NSEG * (NB/2)]; // 16 MB u16-packed
__device__ float g_spart[BB * NSEG * 2];   // pos, loc partials
__device__ int   g_npart[BB * NSEG];
__device__ float g_loc[BB], g_pos[BB], g_neg[BB];
__device__ int   g_npos[BB], g_nneg[BB];

// Dynamic scratch, zeroed by ONE small hipMemsetAsync (4 KB) each call:
// [0, BB*GG*2)  u64 per-(b,g) force-match keys (global atomicMax)
// [+2]          done counter for the last-block final combine
// R7 post-mortem: the per-image GLOBAL hist atomicAdd path (~1M device-scope
// RMWs -> 29 MB memory-side writes, VALUBusy 4%) is deleted; hist is back in
// LDS with deterministic partial writeout.
#define DYN_U32 (BB * GG * 2 + 2)
__device__ unsigned int g_dyn[DYN_U32];
__device__ __forceinline__ unsigned long long* fkeyp() {
    return (unsigned long long*)g_dyn;               // 8-aligned
}
__device__ __forceinline__ int* donep() {
    return (int*)(g_dyn + BB * GG * 2);
}

__device__ __forceinline__ float midval(int bin) {
    return __uint_as_float((((unsigned int)bin + KOFF) << 14) | 8192u);
}

// ---------------------------------------------------------------------------
// Kernel 1: fused per-anchor match + per-gt force-match.
// grid (MBLK, B), block 256, AT=4 anchors/thread (strided, coalesced).
// Divide-free scoring: r = inter/(areaA+areaG), monotone in IoU (iou=r/(1-r)),
// argmax-equivalent; iou>0.5 <=> r>1/3. rcp 1-ulp absorbed by bf16 budget
// (R2-R7 benches: absmax 0.0).
// Reduction (R6-proven): per gt, thread reduces its 4 candidates in registers
// to key=(r_bits<<32)|(~offset) (tie-break = lowest offset, exact), 6-level
// __shfl_xor u64 butterfly, lane0 -> wkey[wave][g]; after barrier t<32 folds
// the 4 wave partials and fires ONE global atomicMax into fkey[b][g] with the
// GLOBAL anchor id in the low word (64 blocks/image x 32 keys: negligible).
__global__ void __launch_bounds__(256, 4)
k_matchforce(const float4* __restrict__ anchors,
             const float4* __restrict__ gts) {
    __shared__ float4 sg[GG];
    __shared__ unsigned long long wkey[4][GG];
    const int b = blockIdx.y;
    const int t = threadIdx.x;
    const int wave = t >> 6, lane = t & 63;
    if (t < GG) sg[t] = gts[(size_t)b * GG + t];
    __syncthreads();

    const size_t abase = (size_t)b * AA + (size_t)blockIdx.x * APB;

    float ax0[AT], ay0[AT], ax1[AT], ay1[AT], aar[AT], best[AT];
    int bg[AT];
#pragma unroll
    for (int j = 0; j < AT; ++j) {
        const float4 av = anchors[abase + j * 256 + t];
        ax0[j] = av.x; ay0[j] = av.y; ax1[j] = av.z; ay1[j] = av.w;
        aar[j] = (av.z - av.x) * (av.w - av.y);
        best[j] = -1.0f; bg[j] = 0;
    }

#pragma unroll 2
    for (int g = 0; g < GG; ++g) {
        const float4 gb = sg[g];
        const float ga = (gb.z - gb.x) * (gb.w - gb.y);
        float fbest = -1.0f;              // r >= 0 always -> j=0 wins init
        int fo = t;                       // block-local offset of j=0 anchor
#pragma unroll
        for (int j = 0; j < AT; ++j) {
            const float lx = fmaxf(ax0[j], gb.x), ly = fmaxf(ay0[j], gb.y);
            const float rx = fminf(ax1[j], gb.z), ry = fminf(ay1[j], gb.w);
            const float w = fmaxf(rx - lx, 0.0f), h = fmaxf(ry - ly, 0.0f);
            const float inter = w * h;
            const float s = aar[j] + ga;                    // areaA + areaG > 0
            const float r = inter * __builtin_amdgcn_rcpf(s);
            if (r > best[j]) { best[j] = r; bg[j] = g; }    // strict >: first max
            if (r > fbest)   { fbest = r; fo = j * 256 + t; }
        }
        // packed key: fbest >= 0 so float bits are unsigned-monotone; low word
        // = ~offset so larger key == smaller anchor offset on value ties.
        unsigned long long key =
            ((unsigned long long)__float_as_uint(fbest) << 32) |
            (unsigned long long)(0xFFFFFFFFu - (unsigned int)fo);
#pragma unroll
        for (int off = 1; off < 64; off <<= 1) {
            const unsigned long long o = __shfl_xor(key, off, 64);
            if (o > key) key = o;
        }
        if (lane == 0) wkey[wave][g] = key;
    }

#pragma unroll
    for (int j = 0; j < AT; ++j) {
        g_mask[abase + j * 256 + t] = (best[j] > (1.0f / 3.0f)) ? 1 : 0;
        g_bidx[abase + j * 256 + t] = (unsigned char)bg[j];
    }
    __syncthreads();
    if (t < GG) {
        unsigned long long k = wkey[0][t];
#pragma unroll
        for (int w = 1; w < 4; ++w) {
            const unsigned long long k1 = wkey[w][t];
            if (k1 > k) k = k1;
        }
        // re-pack low word with the GLOBAL anchor id; fire one device atomic.
        const unsigned int off = 0xFFFFFFFFu - (unsigned int)(k & 0xFFFFFFFFull);
        const unsigned int ga = (unsigned int)(blockIdx.x * APB) + off;
        atomicMax(&fkeyp()[b * GG + t],
                  (k & 0xFFFFFFFF00000000ull) |
                  (unsigned long long)(0xFFFFFFFFu - ga));
    }
}

// ---------------------------------------------------------------------------
// Kernel 2: segmented per-image stats. grid (NSEG=64, B), block 256 ->
// 1024 blocks (4/CU, 16 waves/CU).
// Forced positives: read the 32 folded fkeys (256 B), mark in-segment winners
// in a 128 B LDS bitmap. Positive = g_mask OR bitmap bit.
// Negatives: LDS hist packed 2 bins/u32 (u16 counts; block sees <=1024
// negatives -> no overflow), deterministic 16 KB partial writeout per block.
// NO global atomics on the hot path (R7 lesson).
__global__ void k_stats(const float4* __restrict__ bbox,
                        const float* __restrict__ conf,
                        const float4* __restrict__ gts) {
    __shared__ float4 sg[GG];
    __shared__ unsigned int hp[NB / 2];       // 16 KB packed hist
    __shared__ unsigned int bmap[SEGA / 32];  // 128 B forced-positive bitmap
    __shared__ float rf[256], rf2[256];
    __shared__ unsigned int ru[256];
    const int b = blockIdx.y, seg = blockIdx.x, t = threadIdx.x;
    if (t < GG) sg[t] = gts[(size_t)b * GG + t];
    for (int j = t; j < NB / 2; j += 256) hp[j] = 0u;
    if (t < SEGA / 32) bmap[t] = 0u;
    __syncthreads();
    if (t < GG) {
        const unsigned long long k = fkeyp()[b * GG + t];
        const unsigned int a = 0xFFFFFFFFu - (unsigned int)(k & 0xFFFFFFFFull);
        const int la = (int)a - seg * SEGA;
        if (la >= 0 && la < SEGA) atomicOr(&bmap[la >> 5], 1u << (la & 31));
    }
    __syncthreads();

    const size_t base = (size_t)b * AA + (size_t)seg * SEGA;   // anchor units
    const float4* c4 = (const float4*)(conf + base);
    const uchar4* m4 = (const uchar4*)(g_mask + base);
    const uchar4* x4 = (const uchar4*)(g_bidx + base);
    const float4* bb4 = bbox + base;

    float pos = 0.0f, loc = 0.0f;
    int np = 0;
    {
        const int idx = t;                     // 4 consecutive anchors/thread
        const float4 p4 = c4[idx];
        const uchar4 mm = m4[idx];
        const uchar4 xx = x4[idx];
        const unsigned int bw = (bmap[idx >> 3] >> ((idx & 7) * 4)) & 0xFu;
        const float pv[4] = {p4.x, p4.y, p4.z, p4.w};
        const unsigned char mv[4] = {mm.x, mm.y, mm.z, mm.w};
        const unsigned char xv[4] = {xx.x, xx.y, xx.z, xx.w};
#pragma unroll
        for (int c = 0; c < 4; ++c) {
            const float p = pv[c];
            if (mv[c] | ((bw >> c) & 1u)) {
                np += 1;
                pos += -logf(p);
                const float4 bv = bb4[4 * idx + c];
                const float4 gb = sg[xv[c]];
                const float d0 = (bv.x + bv.z) * 0.5f - (gb.x + gb.z) * 0.5f;
                const float d1 = (bv.y + bv.w) * 0.5f - (gb.y + gb.w) * 0.5f;
                const float d2 = (bv.z - bv.x) - (gb.z - gb.x);
                const float d3 = (bv.w - bv.y) - (gb.w - gb.y);
                float ds[4] = {d0, d1, d2, d3};
#pragma unroll
                for (int q = 0; q < 4; ++q) {
                    float ax = fabsf(ds[q]);
                    loc += (ax < 1.0f) ? 0.5f * ax * ax : ax - 0.5f;
                }
            } else {
                const float nb = -log1pf(-p);
                int key = (int)(__float_as_uint(nb) >> 14) - (int)KOFF;
                key = key < 0 ? 0 : (key > NB - 1 ? NB - 1 : key);
                atomicAdd(&hp[key >> 1], 1u << ((key & 1) << 4));
            }
        }
    }
    // block reduce np/pos/loc (barriers also fence the LDS hist atomics)
    ru[t] = (unsigned int)np; rf[t] = pos; rf2[t] = loc;
    __syncthreads();
    for (int w = 128; w > 0; w >>= 1) {
        if (t < w) { ru[t] += ru[t + w]; rf[t] += rf[t + w]; rf2[t] += rf2[t + w]; }
        __syncthreads();
    }
    if (t == 0) {
        g_npart[b * NSEG + seg] = (int)ru[0];
        g_spart[(b * NSEG + seg) * 2 + 0] = rf[0];
        g_spart[(b * NSEG + seg) * 2 + 1] = rf2[0];
    }
    unsigned int* outp = g_hpart + ((size_t)b * NSEG + seg) * (NB / 2);
    for (int j = t; j < NB / 2; j += 256) outp[j] = hp[j];
}

// ---------------------------------------------------------------------------
// Kernel 3: per-image fold + hard-negative top-k + (last block) final combine.
// grid B, block 1024. Folds the 64 u16-packed partial hists (coalesced, 1 MB
// per image); seg partials folded wave-parallel (t<64 + shfl).
// Cross-block handoff: __threadfence + done counter; 16th block agent-scope
// loads and writes the dual-bf16-encoded output.
__global__ void __launch_bounds__(1024) k_select(unsigned int* __restrict__ out) {
    __shared__ unsigned int hist[NB];         // 32 KB
    __shared__ unsigned int ru[1024];
    __shared__ unsigned int s2[32];
    __shared__ float sh_pos, sh_loc;
    __shared__ int sh_np, sh_k, sh_bsel;
    __shared__ unsigned int sh_take;
    __shared__ float rf[1024];

    const int b = blockIdx.x, t = threadIdx.x;
    // fold 64 packed partial hists -> u32 LDS hist
    for (int w = t; w < NB / 2; w += 1024) {
        unsigned int lo = 0, hi = 0;
#pragma unroll 8
        for (int s = 0; s < NSEG; ++s) {
            const unsigned int v = g_hpart[((size_t)b * NSEG + s) * (NB / 2) + w];
            lo += v & 0xFFFFu; hi += v >> 16;
        }
        hist[2 * w] = lo; hist[2 * w + 1] = hi;
    }
    if (t < 64) {                             // wave-parallel seg-partial fold
        int np = g_npart[b * NSEG + t];
        float pos = g_spart[(b * NSEG + t) * 2 + 0];
        float loc = g_spart[(b * NSEG + t) * 2 + 1];
#pragma unroll
        for (int off = 32; off > 0; off >>= 1) {
            np  += __shfl_xor(np,  off, 64);
            pos += __shfl_xor(pos, off, 64);
            loc += __shfl_xor(loc, off, 64);
        }
        if (t == 0) { sh_np = np; sh_pos = pos; sh_loc = loc; }
    }
    __syncthreads();
    const int np_tot = sh_np;

    // descending chunk counts: thread t covers bins NB-1-8t .. NB-8-8t
    unsigned int c = 0;
    const int hi = NB - 1 - t * 8;
#pragma unroll
    for (int j = 0; j < 8; ++j) c += hist[hi - j];
    ru[t] = c;
    __syncthreads();
    if (t < 32) {
        unsigned int x = 0;
#pragma unroll
        for (int j = 0; j < 32; ++j) x += ru[t * 32 + j];
        s2[t] = x;
    }
    __syncthreads();
    if (t == 0) {
        int k = 3 * np_tot;
        const int maxneg = AA - np_tot;
        if (k > maxneg) k = maxneg;
        sh_k = k;
        int bsel = NB;            // NB => nothing selected
        unsigned int take = 0;
        if (k > 0) {
            unsigned int cum = 0;
            int u = 0;
            while (u < 31 && cum + s2[u] < (unsigned int)k) { cum += s2[u]; ++u; }
            int cc = u * 32;
            while (cc < 1023 && cum + ru[cc] < (unsigned int)k) { cum += ru[cc]; ++cc; }
            const int h2 = NB - 1 - cc * 8;
            int j = 0;
            while (j < 7 && cum + hist[h2 - j] < (unsigned int)k) { cum += hist[h2 - j]; ++j; }
            bsel = h2 - j;
            take = (unsigned int)k - cum;
        }
        sh_bsel = bsel; sh_take = take;
    }
    __syncthreads();
    const int bsel = sh_bsel;
    float negp = 0.0f;
    for (int j = t; j < NB; j += 1024)
        if (j > bsel) { unsigned int cnt = hist[j]; if (cnt) negp += (float)cnt * midval(j); }
    rf[t] = negp;
    __syncthreads();
    for (int w = 512; w > 0; w >>= 1) {
        if (t < w) rf[t] += rf[t + w];
        __syncthreads();
    }
    if (t == 0) {
        float neg = 0.0f;
        if (sh_k > 0) neg = rf[0] + (float)sh_take * midval(bsel < NB ? bsel : 0);
        g_loc[b] = sh_loc; g_pos[b] = sh_pos; g_neg[b] = neg;
        g_npos[b] = np_tot; g_nneg[b] = sh_k;

        __threadfence();                        // publish before counting in
        const int old = atomicAdd(donep(), 1);
        if (old == BB - 1) {                    // last image: final combine
            __threadfence();
            float loc = 0.0f, conf = 0.0f;
            int tot = 0;
            for (int bb = 0; bb < BB; ++bb) {
                const float lv = __hip_atomic_load(&g_loc[bb],  __ATOMIC_RELAXED, __HIP_MEMORY_SCOPE_AGENT);
                const float pv = __hip_atomic_load(&g_pos[bb],  __ATOMIC_RELAXED, __HIP_MEMORY_SCOPE_AGENT);
                const float nv = __hip_atomic_load(&g_neg[bb],  __ATOMIC_RELAXED, __HIP_MEMORY_SCOPE_AGENT);
                const int   np = __hip_atomic_load(&g_npos[bb], __ATOMIC_RELAXED, __HIP_MEMORY_SCOPE_AGENT);
                const int   nn = __hip_atomic_load(&g_nneg[bb], __ATOMIC_RELAXED, __HIP_MEMORY_SCOPE_AGENT);
                loc += lv;
                conf += pv / (float)(np > 1 ? np : 1) +
                        nv / (float)(nn > 1 ? nn : 1);
                tot += np;
            }
            const float total = loc / (float)(tot > 1 ? tot : 1) + conf / (float)BB;
            const unsigned int u = __float_as_uint(total);
            const unsigned int r = 0x7FFFu + ((u >> 16) & 1u);
            const unsigned int bf = (u + r) >> 16;      // bf16(total), RNE
            out[0] = (bf << 16) | bf;
        }
    }
}

extern "C" void kernel_launch(void* const* d_in, const int* in_sizes, int n_in,
                              void* d_out, int out_size, void* d_ws, size_t ws_size,
                              hipStream_t stream) {
    const float4* bbox    = (const float4*)d_in[0];
    const float*  conf    = (const float*)d_in[1];
    const float4* anchors = (const float4*)d_in[2];
    const float4* gts     = (const float4*)d_in[3];

    static unsigned int* dynp = nullptr;       // cached symbol address
    if (!dynp) hipGetSymbolAddress((void**)&dynp, HIP_SYMBOL(g_dyn));
    hipMemsetAsync(dynp, 0, sizeof(unsigned int) * DYN_U32, stream);

    k_matchforce<<<dim3(MBLK, BB), 256, 0, stream>>>(anchors, gts);
    k_stats<<<dim3(NSEG, BB), 256, 0, stream>>>(bbox, conf, gts);
    k_select<<<BB, 1024, 0, stream>>>((unsigned int*)d_out);
}